// Round 1
// 1021.679 us; speedup vs baseline: 1.0553x; 1.0553x over previous
//
// Hyperbolic (Poincare ball) transformer block — MI355X round 6.
// Round-5 + fast-math epilogues: all row-wise kernels (stage1, epi_qkv,
// epi_attnout, epi_ffn1, epi_final, expmap_rows) were VALU-bound
// (VALUBusy 85%, HBM 39%) from libm atanhf/tanhf and IEEE divides.
// Replaced with 1-instr HW ops:
//   rcp  = v_rcp_f32, rsq = v_rsq_f32
//   atanh(x) = 0.3465736 * v_log_f32((1+x)*rcp(1-x))   (1-x exact, Sterbenz)
//   tanh(x>=0) = (1-t)*rcp(1+t), t = v_exp_f32(-2x*log2e)
//   1/sqrt(s), n = s*rsq(s) fused; ps*atanh(ne)/ne == atanh(ne)/un (exact)
//   bf16 pack via native __bf16 cast (v_cvt_pk_bf16_f32, same RNE bits)
// GEMM (m97 structure) and MFMA flash attention unchanged.
#include <hip/hip_runtime.h>
#include <math.h>

#define S_DIM 128
#define B_DIM 256
#define E_DIM 512
#define F_DIM 2048
#define N_ROWS (S_DIM * B_DIM) /* 32768 */
#define CH 4096                /* FFN row chunk */
#define MAXN 0.99999f          /* 1 - 1e-5 */

typedef __bf16 bf16x8 __attribute__((ext_vector_type(8)));
typedef float f32x4 __attribute__((ext_vector_type(4)));

// ---- fast-math helpers (1-instr HW transcendentals) -----------------------
__device__ __forceinline__ float frcp(float x) { return __builtin_amdgcn_rcpf(x); }
__device__ __forceinline__ float frsq(float x) { return __builtin_amdgcn_rsqf(x); }
__device__ __forceinline__ float fexp2(float x) { return __builtin_amdgcn_exp2f(x); }
__device__ __forceinline__ float flog2(float x) { return __builtin_amdgcn_logf(x); }
// atanh(x), x in [0,1): 0.5*ln((1+x)/(1-x)); 1-x exact for x in [0.5,1],
// and for x<0.5 no cancellation. 0.34657359 = 0.5*ln(2).
__device__ __forceinline__ float fatanh(float x) {
  return 0.34657359f * flog2((1.f + x) * frcp(1.f - x));
}
// tanh(x) for x >= 0: (1-e^-2x)/(1+e^-2x). -2/ln2 = -2.88539008.
__device__ __forceinline__ float ftanh(float x) {
  float t = fexp2(x * -2.88539008f);
  return (1.f - t) * frcp(1.f + t);
}

__device__ __forceinline__ ushort f2bf(float f) {
  __bf16 h = (__bf16)f;  // native v_cvt_pk_bf16_f32, RNE (same bits as manual)
  return __builtin_bit_cast(ushort, h);
}
__device__ __forceinline__ uint pack2(float a, float b) {
  return (uint)f2bf(a) | ((uint)f2bf(b) << 16);
}

__device__ __forceinline__ void gld16(const ushort* g, ushort* l) {
  __builtin_amdgcn_global_load_lds(
      (const __attribute__((address_space(1))) void*)g,
      (__attribute__((address_space(3))) void*)l, 16, 0, 0);
}

// ---- wave-wide butterfly reduction of K values (all lanes get results) ----
template <int K>
__device__ __forceinline__ void waveRed(float (&v)[K]) {
#pragma unroll
  for (int o = 1; o < 64; o <<= 1) {
#pragma unroll
    for (int i = 0; i < K; ++i) v[i] += __shfl_xor(v[i], o);
  }
}

// ---------------- fp32 -> bf16 convert (weights) ---------------------------
__global__ __launch_bounds__(256) void k_f2bf(const float* __restrict__ in,
                                              ushort* __restrict__ out, int n) {
  for (int i = blockIdx.x * 256 + threadIdx.x; i < n; i += gridDim.x * 256)
    out[i] = f2bf(in[i]);
}

// ---- stage 1: h1 = expmap0(LN(logmap0(x))) -> bf16, |h1| fp32. Wave/row. --
__global__ __launch_bounds__(256) void k_stage1(const float* __restrict__ x,
                                                const float* __restrict__ g,
                                                const float* __restrict__ bb,
                                                ushort* __restrict__ h,
                                                float* __restrict__ hn) {
  int row = blockIdx.x * 4 + (threadIdx.x >> 6);
  int lane = threadIdx.x & 63;
  size_t base = (size_t)row * E_DIM + lane * 8;
  float v[8], gv[8], bv[8];
  *(float4*)&v[0] = *(const float4*)(x + base);
  *(float4*)&v[4] = *(const float4*)(x + base + 4);
  *(float4*)&gv[0] = *(const float4*)(g + lane * 8);
  *(float4*)&gv[4] = *(const float4*)(g + lane * 8 + 4);
  *(float4*)&bv[0] = *(const float4*)(bb + lane * 8);
  *(float4*)&bv[4] = *(const float4*)(bb + lane * 8 + 4);
  float s[2] = {0.f, 0.f};
#pragma unroll
  for (int i = 0; i < 8; ++i) { s[0] += v[i] * v[i]; s[1] += v[i]; }
  waveRed<2>(s);
  float se = s[0] + 1e-30f;
  float rn = frsq(se);
  float n = se * rn;
  float a = fatanh(fminf(n, MAXN)) * rn;
  float mu = a * s[1] * (1.f / 512.f);
  float var = fmaxf(a * a * s[0] * (1.f / 512.f) - mu * mu, 0.f);
  float rstd = frsq(var + 1e-5f);
  float e[8];
  float s2[1] = {0.f};
#pragma unroll
  for (int i = 0; i < 8; ++i) {
    e[i] = (a * v[i] - mu) * rstd * gv[i] + bv[i];
    s2[0] += e[i] * e[i];
  }
  waveRed<1>(s2);
  float se2 = s2[0] + 1e-30f;
  float rn2 = frsq(se2);
  float n2 = se2 * rn2;
  float th = ftanh(n2);
  float f = th * rn2;
  uint4 o = {pack2(e[0] * f, e[1] * f), pack2(e[2] * f, e[3] * f),
             pack2(e[4] * f, e[5] * f), pack2(e[6] * f, e[7] * f)};
  *reinterpret_cast<uint4*>(h + base) = o;
  if (lane == 0) hn[row] = th;
}

// -------- bf16 MFMA GEMM: C[n][m] = sum_k A[n][k]*B[m][k], C fp32 ----------
__global__ __launch_bounds__(256) void k_gemm_bf16(
    const ushort* __restrict__ A, const ushort* __restrict__ B,
    float* __restrict__ C, int K, int M, int kseg,
    unsigned long long partStride) {
  __shared__ __align__(16) ushort As[128 * 32];
  __shared__ __align__(16) ushort Bs[128 * 32];
  int tid = threadIdx.x;
  int w = tid >> 6, lane = tid & 63;
  int wm = w >> 1, wn = w & 1;
  size_t row0 = (size_t)blockIdx.y * 128;
  size_t col0 = (size_t)blockIdx.x * 128;
  int k0 = blockIdx.z * kseg;

  const ushort* gA =
      A + (row0 + w * 32 + (lane >> 2)) * (size_t)K + (lane & 3) * 8 + k0;
  const ushort* gB =
      B + (col0 + w * 32 + (lane >> 2)) * (size_t)K + (lane & 3) * 8 + k0;
  ushort* lA = As + (w * 32) * 32;
  ushort* lB = Bs + (w * 32) * 32;
  const int rowK16 = 16 * K;

  int fro = (lane & 15) * 32 + (lane >> 4) * 8;
  const ushort* raA = As + (wm * 64) * 32 + fro;
  const ushort* raB = Bs + (wn * 64) * 32 + fro;

  f32x4 zero = {0.f, 0.f, 0.f, 0.f};
  f32x4 acc[4][4];
#pragma unroll
  for (int i = 0; i < 4; ++i)
#pragma unroll
    for (int j = 0; j < 4; ++j) acc[i][j] = zero;

  for (int kt = 0; kt < kseg; kt += 32) {
    __syncthreads();
    gld16(gA + kt, lA);
    gld16(gA + kt + rowK16, lA + 16 * 32);
    gld16(gB + kt, lB);
    gld16(gB + kt + rowK16, lB + 16 * 32);
    __syncthreads();
    bf16x8 af[4], bfv[4];
#pragma unroll
    for (int t = 0; t < 4; ++t) {
      af[t] = *reinterpret_cast<const bf16x8*>(raA + t * 512);
      bfv[t] = *reinterpret_cast<const bf16x8*>(raB + t * 512);
    }
#pragma unroll
    for (int i = 0; i < 4; ++i)
#pragma unroll
      for (int j = 0; j < 4; ++j)
        acc[i][j] = __builtin_amdgcn_mfma_f32_16x16x32_bf16(af[i], bfv[j],
                                                            acc[i][j], 0, 0, 0);
  }
  float* Cz = C + (size_t)blockIdx.z * partStride;
  int crow = wm * 64 + (lane >> 4) * 4;
  int ccol = (int)col0 + wn * 64 + (lane & 15);
#pragma unroll
  for (int ti = 0; ti < 4; ++ti) {
    size_t r = row0 + crow + ti * 16;
#pragma unroll
    for (int tj = 0; tj < 4; ++tj) {
      int cc = ccol + tj * 16;
#pragma unroll
      for (int reg = 0; reg < 4; ++reg)
        Cz[(r + reg) * (size_t)M + cc] = acc[ti][tj][reg];
    }
  }
}

// ---- QKV epilogue (wave/row, 1 pass): logmap0(projx(mobius_add(mv,b))) ----
__global__ __launch_bounds__(256) void k_epi_qkv(const float* __restrict__ mx,
                                                 const float* __restrict__ xn_arr,
                                                 const float* __restrict__ bias,
                                                 ushort* __restrict__ qout) {
  int row = blockIdx.x * 4 + (threadIdx.x >> 6);
  int lane = threadIdx.x & 63;
  size_t base = (size_t)row * E_DIM + lane * 8;
  float m[8], bv[8];
  *(float4*)&m[0] = *(const float4*)(mx + base);
  *(float4*)&m[4] = *(const float4*)(mx + base + 4);
  *(float4*)&bv[0] = *(const float4*)(bias + lane * 8);
  *(float4*)&bv[4] = *(const float4*)(bias + lane * 8 + 4);
  float s[3] = {0.f, 0.f, 0.f};
#pragma unroll
  for (int i = 0; i < 8; ++i) {
    s[0] += m[i] * m[i]; s[1] += m[i] * bv[i]; s[2] += bv[i] * bv[i];
  }
  waveRed<3>(s);
  float se = s[0] + 1e-30f;
  float rmx = frsq(se);
  float mxn = se * rmx;
  float xn = xn_arr[row];
  float aa = fatanh(fminf(xn, MAXN));
  float tt = ftanh(mxn * frcp(xn) * aa);
  float c = tt * rmx;
  float xy = c * s[1], y2 = s[2], x2 = tt * tt;
  float c1 = 1.f + 2.f * xy + y2, c2 = 1.f - x2;
  float iden = frcp(fmaxf(1.f + 2.f * xy + x2 * y2, 1e-15f));
  float cc1 = c1 * c * iden, cc2 = c2 * iden;
  float un2 = fmaxf(cc1 * cc1 * s[0] + 2.f * cc1 * cc2 * s[1] + cc2 * cc2 * s[2], 0.f);
  float ue = un2 + 1e-30f;
  float run = frsq(ue);
  float un = ue * run;
  float ne = fminf(un, MAXN);
  // ps*atanh(ne)/ne == atanh(ne)/un in both clip branches (exact identity)
  float f = fatanh(ne) * run;
  float u[8];
#pragma unroll
  for (int i = 0; i < 8; ++i) u[i] = (cc1 * m[i] + cc2 * bv[i]) * f;
  uint4 o = {pack2(u[0], u[1]), pack2(u[2], u[3]), pack2(u[4], u[5]),
             pack2(u[6], u[7])};
  *reinterpret_cast<uint4*>(qout + base) = o;
}

// ---- attention: per (b,h) MFMA tile (unchanged from round 4) --------------
__global__ __launch_bounds__(256) void k_attn(const ushort* __restrict__ q,
                                              const ushort* __restrict__ k,
                                              const ushort* __restrict__ v,
                                              float* __restrict__ o) {
  __shared__ __align__(16) ushort smem[27136];
  ushort* Qs = smem;
  ushort* Ks = smem + 9216;
  ushort* VTs = smem + 18432;
  ushort* Ps = smem;
  int bh = blockIdx.x;
  int b = bh >> 3, h = bh & 7;
  int tid = threadIdx.x;
  int w = tid >> 6, lane = tid & 63;
  const size_t BE = (size_t)B_DIM * E_DIM;
  size_t gbase = (size_t)b * E_DIM + (size_t)h * 64;

  {
    int s = tid >> 1, half = (tid & 1) * 32;
    const ushort* qr = q + gbase + (size_t)s * BE + half;
    const ushort* kr = k + gbase + (size_t)s * BE + half;
    const ushort* vr = v + gbase + (size_t)s * BE + half;
#pragma unroll
    for (int j = 0; j < 4; ++j) {
      *reinterpret_cast<uint4*>(&Qs[s * 72 + half + j * 8]) =
          *reinterpret_cast<const uint4*>(qr + j * 8);
      *reinterpret_cast<uint4*>(&Ks[s * 72 + half + j * 8]) =
          *reinterpret_cast<const uint4*>(kr + j * 8);
    }
    ushort tv[32];
#pragma unroll
    for (int j = 0; j < 4; ++j)
      *reinterpret_cast<uint4*>(&tv[j * 8]) =
          *reinterpret_cast<const uint4*>(vr + j * 8);
#pragma unroll
    for (int d = 0; d < 32; ++d) VTs[(half + d) * 136 + s] = tv[d];
  }
  __syncthreads();

  f32x4 zero = {0.f, 0.f, 0.f, 0.f};
  f32x4 sacc[2][8];
#pragma unroll
  for (int i = 0; i < 2; ++i)
#pragma unroll
    for (int j = 0; j < 8; ++j) sacc[i][j] = zero;
  {
    const ushort* qb = Qs + (w * 32 + (lane & 15)) * 72 + (lane >> 4) * 8;
    const ushort* kb = Ks + (lane & 15) * 72 + (lane >> 4) * 8;
#pragma unroll
    for (int kk = 0; kk < 2; ++kk) {
      bf16x8 a0 = *reinterpret_cast<const bf16x8*>(qb + kk * 32);
      bf16x8 a1 = *reinterpret_cast<const bf16x8*>(qb + 16 * 72 + kk * 32);
#pragma unroll
      for (int tj = 0; tj < 8; ++tj) {
        bf16x8 bf = *reinterpret_cast<const bf16x8*>(kb + tj * 16 * 72 + kk * 32);
        sacc[0][tj] = __builtin_amdgcn_mfma_f32_16x16x32_bf16(a0, bf,
                                                              sacc[0][tj], 0, 0, 0);
        sacc[1][tj] = __builtin_amdgcn_mfma_f32_16x16x32_bf16(a1, bf,
                                                              sacc[1][tj], 0, 0, 0);
      }
    }
  }

#pragma unroll
  for (int ti = 0; ti < 2; ++ti) {
#pragma unroll
    for (int r = 0; r < 4; ++r) {
      float mx = -1e30f;
#pragma unroll
      for (int tj = 0; tj < 8; ++tj) mx = fmaxf(mx, sacc[ti][tj][r]);
      mx = fmaxf(mx, __shfl_xor(mx, 1));
      mx = fmaxf(mx, __shfl_xor(mx, 2));
      mx = fmaxf(mx, __shfl_xor(mx, 4));
      mx = fmaxf(mx, __shfl_xor(mx, 8));
      float l = 0.f;
#pragma unroll
      for (int tj = 0; tj < 8; ++tj) {
        float e = fexp2((sacc[ti][tj][r] - mx) * (0.125f * 1.44269504f));
        sacc[ti][tj][r] = e;
        l += e;
      }
      l += __shfl_xor(l, 1);
      l += __shfl_xor(l, 2);
      l += __shfl_xor(l, 4);
      l += __shfl_xor(l, 8);
      float inv = frcp(l);
#pragma unroll
      for (int tj = 0; tj < 8; ++tj) sacc[ti][tj][r] *= inv;
    }
  }

  __syncthreads();
  {
    int qr0 = w * 32 + (lane >> 4) * 4;
    int kc = lane & 15;
#pragma unroll
    for (int ti = 0; ti < 2; ++ti)
#pragma unroll
      for (int tj = 0; tj < 8; ++tj)
#pragma unroll
        for (int r = 0; r < 4; ++r)
          Ps[(qr0 + ti * 16 + r) * 136 + tj * 16 + kc] =
              f2bf(sacc[ti][tj][r]);
  }
  __syncthreads();

  f32x4 oacc[2][4];
#pragma unroll
  for (int i = 0; i < 2; ++i)
#pragma unroll
    for (int j = 0; j < 4; ++j) oacc[i][j] = zero;
  {
    const ushort* pb = Ps + (w * 32 + (lane & 15)) * 136 + (lane >> 4) * 8;
    const ushort* vb = VTs + (lane & 15) * 136 + (lane >> 4) * 8;
#pragma unroll
    for (int kk = 0; kk < 4; ++kk) {
      bf16x8 a0 = *reinterpret_cast<const bf16x8*>(pb + kk * 32);
      bf16x8 a1 = *reinterpret_cast<const bf16x8*>(pb + 16 * 136 + kk * 32);
#pragma unroll
      for (int tj = 0; tj < 4; ++tj) {
        bf16x8 bv = *reinterpret_cast<const bf16x8*>(vb + tj * 16 * 136 + kk * 32);
        oacc[0][tj] = __builtin_amdgcn_mfma_f32_16x16x32_bf16(a0, bv,
                                                              oacc[0][tj], 0, 0, 0);
        oacc[1][tj] = __builtin_amdgcn_mfma_f32_16x16x32_bf16(a1, bv,
                                                              oacc[1][tj], 0, 0, 0);
      }
    }
  }

  {
    int qr0 = w * 32 + (lane >> 4) * 4;
    int dc = lane & 15;
#pragma unroll
    for (int ti = 0; ti < 2; ++ti)
#pragma unroll
      for (int tj = 0; tj < 4; ++tj)
#pragma unroll
        for (int r = 0; r < 4; ++r)
          o[(size_t)(qr0 + ti * 16 + r) * BE + gbase + tj * 16 + dc] =
              oacc[ti][tj][r];
  }
}

// ---- expmap0 rowwise (wave/row, 1 pass) -----------------------------------
__global__ __launch_bounds__(256) void k_expmap_rows(const float* __restrict__ in,
                                                     ushort* __restrict__ out,
                                                     float* __restrict__ nrm) {
  int row = blockIdx.x * 4 + (threadIdx.x >> 6);
  int lane = threadIdx.x & 63;
  size_t base = (size_t)row * E_DIM + lane * 8;
  float v[8];
  *(float4*)&v[0] = *(const float4*)(in + base);
  *(float4*)&v[4] = *(const float4*)(in + base + 4);
  float s[1] = {0.f};
#pragma unroll
  for (int i = 0; i < 8; ++i) s[0] += v[i] * v[i];
  waveRed<1>(s);
  float se = s[0] + 1e-30f;
  float rn = frsq(se);
  float n = se * rn;
  float th = ftanh(n);
  float f = th * rn;
  uint4 o = {pack2(v[0] * f, v[1] * f), pack2(v[2] * f, v[3] * f),
             pack2(v[4] * f, v[5] * f), pack2(v[6] * f, v[7] * f)};
  *reinterpret_cast<uint4*>(out + base) = o;
  if (lane == 0) nrm[row] = th;
}

// ---- attn-out epilogue (wave/row, 3 passes): man_linear(Wo) + residual
// mobius_add + projx (res2 fp32 in-place) + LN2 chain -> h2 bf16 ------------
__global__ __launch_bounds__(256) void k_epi_attnout(
    float* __restrict__ mo, const float* __restrict__ xn_arr,
    const float* __restrict__ bo, const float* __restrict__ xin,
    const float* __restrict__ g2, const float* __restrict__ b2,
    ushort* __restrict__ h2, float* __restrict__ h2n) {
  int row = blockIdx.x * 4 + (threadIdx.x >> 6);
  int lane = threadIdx.x & 63;
  size_t base = (size_t)row * E_DIM + lane * 8;
  float m[8], bv[8];
  *(float4*)&m[0] = *(const float4*)(mo + base);
  *(float4*)&m[4] = *(const float4*)(mo + base + 4);
  *(float4*)&bv[0] = *(const float4*)(bo + lane * 8);
  *(float4*)&bv[4] = *(const float4*)(bo + lane * 8 + 4);
  float s[5] = {0.f, 0.f, 0.f, 0.f, 0.f};
#pragma unroll
  for (int i = 0; i < 8; ++i) {
    s[0] += m[i] * m[i]; s[1] += m[i] * bv[i]; s[2] += bv[i] * bv[i];
    s[3] += m[i]; s[4] += bv[i];
  }
  waveRed<5>(s);
  float se = s[0] + 1e-30f;
  float rmx = frsq(se);
  float mxn = se * rmx;
  float xn = xn_arr[row];
  float aa = fatanh(fminf(xn, MAXN));
  float tt = ftanh(mxn * frcp(xn) * aa);
  float c = tt * rmx;
  float xy = c * s[1], y2 = s[2], x2 = tt * tt;
  float c1 = 1.f + 2.f * xy + y2, c2 = 1.f - x2;
  float iden = frcp(fmaxf(1.f + 2.f * xy + x2 * y2, 1e-15f));
  float cc1 = c1 * c * iden, cc2 = c2 * iden;
  float un2 = fmaxf(cc1 * cc1 * s[0] + 2.f * cc1 * cc2 * s[1] + cc2 * cc2 * s[2], 0.f);
  float ue = un2 + 1e-30f;
  float run = frsq(ue);
  float un = ue * run;
  float ps = un > MAXN ? MAXN * run : 1.f;
  float zn = fminf(un, MAXN);
  float z[8];
#pragma unroll
  for (int i = 0; i < 8; ++i) z[i] = (cc1 * m[i] + cc2 * bv[i]) * ps;
  float sumz = ps * (cc1 * s[3] + cc2 * s[4]);
  // mobius_add(z, xin) + projx
  float r[8];
  *(float4*)&r[0] = *(const float4*)(xin + base);
  *(float4*)&r[4] = *(const float4*)(xin + base + 4);
  float t2[3] = {0.f, 0.f, 0.f};
#pragma unroll
  for (int i = 0; i < 8; ++i) {
    t2[0] += z[i] * r[i]; t2[1] += r[i] * r[i]; t2[2] += r[i];
  }
  waveRed<3>(t2);
  float xy2 = t2[0], y22 = t2[1], x22 = zn * zn;
  float d1 = 1.f + 2.f * xy2 + y22, d2 = 1.f - x22;
  float iden2 = frcp(fmaxf(1.f + 2.f * xy2 + x22 * y22, 1e-15f));
  float wn2 = fmaxf(iden2 * iden2 *
                        (d1 * d1 * x22 + 2.f * d1 * d2 * xy2 + d2 * d2 * y22),
                    0.f);
  float we = wn2 + 1e-30f;
  float rwn = frsq(we);
  float wn = we * rwn;
  float ps2 = wn > MAXN ? MAXN * rwn : 1.f;
  float w[8];
#pragma unroll
  for (int i = 0; i < 8; ++i) w[i] = (d1 * z[i] + d2 * r[i]) * iden2 * ps2;
  *(float4*)(mo + base) = *(float4*)&w[0];
  *(float4*)(mo + base + 4) = *(float4*)&w[4];
  // logmap0 -> LN2 -> expmap0 -> projx
  float ne = fminf(wn, MAXN);
  float ath = fatanh(ne);        // = lf*ne = sqrt(Sum l^2)
  float lf = ath * frcp(ne);
  float sumw = ps2 * iden2 * (d1 * sumz + d2 * t2[2]);
  float mu = lf * sumw * (1.f / 512.f);
  float var = fmaxf(ath * ath * (1.f / 512.f) - mu * mu, 0.f);
  float rstd = frsq(var + 1e-5f);
  float gv[8], b2v[8];
  *(float4*)&gv[0] = *(const float4*)(g2 + lane * 8);
  *(float4*)&gv[4] = *(const float4*)(g2 + lane * 8 + 4);
  *(float4*)&b2v[0] = *(const float4*)(b2 + lane * 8);
  *(float4*)&b2v[4] = *(const float4*)(b2 + lane * 8 + 4);
  float e[8];
  float s3[1] = {0.f};
#pragma unroll
  for (int i = 0; i < 8; ++i) {
    e[i] = (lf * w[i] - mu) * rstd * gv[i] + b2v[i];
    s3[0] += e[i] * e[i];
  }
  waveRed<1>(s3);
  float s3e = s3[0] + 1e-30f;
  float rn3 = frsq(s3e);
  float n3 = s3e * rn3;
  float en = ftanh(n3);
  float f = en * rn3;
  if (en > MAXN) f *= MAXN * frcp(en);
  uint4 o = {pack2(e[0] * f, e[1] * f), pack2(e[2] * f, e[3] * f),
             pack2(e[4] * f, e[5] * f), pack2(e[6] * f, e[7] * f)};
  *reinterpret_cast<uint4*>(h2 + base) = o;
  if (lane == 0) h2n[row] = fminf(en, MAXN);
}

// ---- FFN1 epilogue (wave/row of F=2048, 2 passes) -> bf16 -----------------
__global__ __launch_bounds__(256) void k_epi_ffn1(const float* __restrict__ mr_,
                                                  const float* __restrict__ xn_arr,
                                                  const float* __restrict__ bias,
                                                  ushort* __restrict__ hid,
                                                  float* __restrict__ hn_out) {
  int row = blockIdx.x * 4 + (threadIdx.x >> 6);
  int lane = threadIdx.x & 63;
  const float* mr = mr_ + (size_t)row * F_DIM + lane * 32;
  const float* br = bias + lane * 32;
  float m[32], bv[32];
#pragma unroll
  for (int j = 0; j < 8; ++j) {
    *(float4*)&m[j * 4] = *(const float4*)(mr + j * 4);
    *(float4*)&bv[j * 4] = *(const float4*)(br + j * 4);
  }
  float s[3] = {0.f, 0.f, 0.f};
#pragma unroll
  for (int i = 0; i < 32; ++i) {
    s[0] += m[i] * m[i]; s[1] += m[i] * bv[i]; s[2] += bv[i] * bv[i];
  }
  waveRed<3>(s);
  float se = s[0] + 1e-30f;
  float rmx = frsq(se);
  float mxn = se * rmx;
  float xn = xn_arr[row];
  float aa = fatanh(fminf(xn, MAXN));
  float tt = ftanh(mxn * frcp(xn) * aa);
  float c = tt * rmx;
  float xy = c * s[1], y2 = s[2], x2 = tt * tt;
  float c1 = 1.f + 2.f * xy + y2, c2 = 1.f - x2;
  float iden = frcp(fmaxf(1.f + 2.f * xy + x2 * y2, 1e-15f));
  float cc1 = c1 * c * iden, cc2 = c2 * iden;
  float un2 = fmaxf(cc1 * cc1 * s[0] + 2.f * cc1 * cc2 * s[1] + cc2 * cc2 * s[2], 0.f);
  float ue = un2 + 1e-30f;
  float run = frsq(ue);
  float un = ue * run;
  float zn = fminf(un, MAXN);
  // atanh(zn)/zn*ps == atanh(zn)/un (exact in both clip branches)
  float lf = fatanh(zn) * run;
  float s2[1] = {0.f};
#pragma unroll
  for (int i = 0; i < 32; ++i) {
    m[i] = fmaxf((cc1 * m[i] + cc2 * bv[i]) * lf, 0.f);
    s2[0] += m[i] * m[i];
  }
  waveRed<1>(s2);
  float s2e = s2[0] + 1e-30f;
  float rrn = frsq(s2e);
  float rn = s2e * rrn;
  float en = ftanh(rn);
  float f = en * rrn;
  if (en > MAXN) f *= MAXN * frcp(en);
  ushort* hr = hid + (size_t)row * F_DIM + lane * 32;
#pragma unroll
  for (int j = 0; j < 4; ++j) {
    uint4 o = {pack2(m[j * 8 + 0] * f, m[j * 8 + 1] * f),
               pack2(m[j * 8 + 2] * f, m[j * 8 + 3] * f),
               pack2(m[j * 8 + 4] * f, m[j * 8 + 5] * f),
               pack2(m[j * 8 + 6] * f, m[j * 8 + 7] * f)};
    *reinterpret_cast<uint4*>(hr + j * 8) = o;
  }
  if (lane == 0) hn_out[row] = fminf(en, MAXN);
}

// ---- final epilogue (wave/row, 2 passes): split-K sum + man_linear(W2) +
// mob_relu + residual mobius_add + projx -> out fp32 ------------------------
__global__ __launch_bounds__(256) void k_epi_final(
    const float* __restrict__ m2a, const float* __restrict__ m2b,
    const float* __restrict__ xn_arr, const float* __restrict__ bias,
    const float* __restrict__ res, float* __restrict__ out) {
  int row = blockIdx.x * 4 + (threadIdx.x >> 6);
  int lane = threadIdx.x & 63;
  size_t base = (size_t)row * E_DIM + lane * 8;
  float m[8], bv[8], ta[8], tb[8];
  *(float4*)&ta[0] = *(const float4*)(m2a + base);
  *(float4*)&ta[4] = *(const float4*)(m2a + base + 4);
  *(float4*)&tb[0] = *(const float4*)(m2b + base);
  *(float4*)&tb[4] = *(const float4*)(m2b + base + 4);
  *(float4*)&bv[0] = *(const float4*)(bias + lane * 8);
  *(float4*)&bv[4] = *(const float4*)(bias + lane * 8 + 4);
  float s[3] = {0.f, 0.f, 0.f};
#pragma unroll
  for (int i = 0; i < 8; ++i) {
    m[i] = ta[i] + tb[i];
    s[0] += m[i] * m[i]; s[1] += m[i] * bv[i]; s[2] += bv[i] * bv[i];
  }
  waveRed<3>(s);
  float se = s[0] + 1e-30f;
  float rmx = frsq(se);
  float mxn = se * rmx;
  float xn = xn_arr[row];
  float aa = fatanh(fminf(xn, MAXN));
  float tt = ftanh(mxn * frcp(xn) * aa);
  float c = tt * rmx;
  float xy = c * s[1], y2 = s[2], x2 = tt * tt;
  float c1 = 1.f + 2.f * xy + y2, c2 = 1.f - x2;
  float iden = frcp(fmaxf(1.f + 2.f * xy + x2 * y2, 1e-15f));
  float cc1 = c1 * c * iden, cc2 = c2 * iden;
  float un2 = fmaxf(cc1 * cc1 * s[0] + 2.f * cc1 * cc2 * s[1] + cc2 * cc2 * s[2], 0.f);
  float ue = un2 + 1e-30f;
  float run = frsq(ue);
  float un = ue * run;
  float zn = fminf(un, MAXN);
  float lf = fatanh(zn) * run;
  float r[8], q[8];
  *(float4*)&q[0] = *(const float4*)(res + base);
  *(float4*)&q[4] = *(const float4*)(res + base + 4);
  float s2[3] = {0.f, 0.f, 0.f};
#pragma unroll
  for (int i = 0; i < 8; ++i) {
    r[i] = fmaxf((cc1 * m[i] + cc2 * bv[i]) * lf, 0.f);
    s2[0] += r[i] * r[i]; s2[1] += r[i] * q[i]; s2[2] += q[i] * q[i];
  }
  waveRed<3>(s2);
  float s2e = s2[0] + 1e-30f;
  float rrn = frsq(s2e);
  float rn = s2e * rrn;
  float en = ftanh(rn);
  float f = en * rrn;
  if (en > MAXN) f *= MAXN * frcp(en);
  float hn = fminf(en, MAXN);
  float xy2 = f * s2[1], y22 = s2[2], x22 = hn * hn;
  float d1 = 1.f + 2.f * xy2 + y22, d2 = 1.f - x22;
  float iden2 = frcp(fmaxf(1.f + 2.f * xy2 + x22 * y22, 1e-15f));
  float wn2 = fmaxf(iden2 * iden2 *
                        (d1 * d1 * x22 + 2.f * d1 * d2 * xy2 + d2 * d2 * y22),
                    0.f);
  float we = wn2 + 1e-30f;
  float rwn = frsq(we);
  float wn = we * rwn;
  float ps2 = wn > MAXN ? MAXN * rwn : 1.f;
  float w[8];
#pragma unroll
  for (int i = 0; i < 8; ++i)
    w[i] = (d1 * r[i] * f + d2 * q[i]) * iden2 * ps2;
  *(float4*)(out + base) = *(float4*)&w[0];
  *(float4*)(out + base + 4) = *(float4*)&w[4];
}

extern "C" void kernel_launch(void* const* d_in, const int* in_sizes, int n_in,
                              void* d_out, int out_size, void* d_ws,
                              size_t ws_size, hipStream_t stream) {
  const float* x   = (const float*)d_in[0];
  const float* g1  = (const float*)d_in[1];
  const float* lb1 = (const float*)d_in[2];
  const float* g2  = (const float*)d_in[3];
  const float* lb2 = (const float*)d_in[4];
  const float* Wq  = (const float*)d_in[5];
  const float* bq  = (const float*)d_in[6];
  const float* Wk  = (const float*)d_in[7];
  const float* bk  = (const float*)d_in[8];
  const float* Wv  = (const float*)d_in[9];
  const float* bv  = (const float*)d_in[10];
  const float* Wo  = (const float*)d_in[11];
  const float* bo  = (const float*)d_in[12];
  const float* W1  = (const float*)d_in[13];
  const float* b1  = (const float*)d_in[14];
  const float* W2  = (const float*)d_in[15];
  const float* b2  = (const float*)d_in[16];
  float* out = (float*)d_out;
  float* ws = (float*)d_ws;

  const size_t NE = (size_t)N_ROWS * E_DIM;          // 16,777,216
  const size_t WF = (4 * (size_t)E_DIM * E_DIM +
                     2 * (size_t)F_DIM * E_DIM) / 2; // 1,572,864 floats
  float* R_b = ws;                   // NE: mx fp32 / attn-out / mo / res2
  float* R_a = ws + NE;              // NE/2: h1_bf16 -> oe_bf16
  float* R_q = ws + NE + NE / 2;     // NE/2: q_bf16 -> h2_bf16
  float* R_k = ws + 2 * NE;          // NE/2: k_bf16 -> m1 fp32 (CH x F)
  float* R_v = ws + 2 * NE + NE / 2; // NE/2: v_bf16 -> hid_bf16 + m2 partials
  ushort* wqb = (ushort*)(ws + 3 * NE);
  ushort* wkb = wqb + (size_t)E_DIM * E_DIM;
  ushort* wvb = wkb + (size_t)E_DIM * E_DIM;
  ushort* wob = wvb + (size_t)E_DIM * E_DIM;
  ushort* w1b = wob + (size_t)E_DIM * E_DIM;
  ushort* w2b = w1b + (size_t)F_DIM * E_DIM;
  float* n_h1 = ws + 3 * NE + WF;
  float* n_oe = n_h1 + N_ROWS;
  float* n_h2 = n_oe + N_ROWS;
  float* n_h3 = n_h2 + N_ROWS;
  const size_t need = (3 * NE + WF + 4 * (size_t)N_ROWS) * sizeof(float);
  if (ws_size < need) return;

  k_f2bf<<<256, 256, 0, stream>>>(Wq, wqb, E_DIM * E_DIM);
  k_f2bf<<<256, 256, 0, stream>>>(Wk, wkb, E_DIM * E_DIM);
  k_f2bf<<<256, 256, 0, stream>>>(Wv, wvb, E_DIM * E_DIM);
  k_f2bf<<<256, 256, 0, stream>>>(Wo, wob, E_DIM * E_DIM);
  k_f2bf<<<512, 256, 0, stream>>>(W1, w1b, F_DIM * E_DIM);
  k_f2bf<<<512, 256, 0, stream>>>(W2, w2b, F_DIM * E_DIM);

  ushort* h1b = (ushort*)R_a;
  ushort* qb = (ushort*)R_q;
  ushort* kb = (ushort*)R_k;
  ushort* vb = (ushort*)R_v;

  // Phase A: stage1 + QKV projections
  k_stage1<<<N_ROWS / 4, 256, 0, stream>>>(x, g1, lb1, h1b, n_h1);
  dim3 gQ(E_DIM / 128, N_ROWS / 128, 1);
  k_gemm_bf16<<<gQ, 256, 0, stream>>>(h1b, wqb, R_b, E_DIM, E_DIM, E_DIM, 0);
  k_epi_qkv<<<N_ROWS / 4, 256, 0, stream>>>(R_b, n_h1, bq, qb);
  k_gemm_bf16<<<gQ, 256, 0, stream>>>(h1b, wkb, R_b, E_DIM, E_DIM, E_DIM, 0);
  k_epi_qkv<<<N_ROWS / 4, 256, 0, stream>>>(R_b, n_h1, bk, kb);
  k_gemm_bf16<<<gQ, 256, 0, stream>>>(h1b, wvb, R_b, E_DIM, E_DIM, E_DIM, 0);
  k_epi_qkv<<<N_ROWS / 4, 256, 0, stream>>>(R_b, n_h1, bv, vb);

  // Phase B: MFMA attention -> R_b fp32; expmap0 -> oe bf16 (R_a, h1 dead)
  k_attn<<<B_DIM * 8, 256, 0, stream>>>(qb, kb, vb, R_b);
  ushort* oeb = (ushort*)R_a;
  k_expmap_rows<<<N_ROWS / 4, 256, 0, stream>>>(R_b, oeb, n_oe);

  // Phase C: Wo projection -> R_b; epilogue: res2 in-place, h2 bf16 -> R_q
  ushort* h2b = (ushort*)R_q;
  k_gemm_bf16<<<gQ, 256, 0, stream>>>(oeb, wob, R_b, E_DIM, E_DIM, E_DIM, 0);
  k_epi_attnout<<<N_ROWS / 4, 256, 0, stream>>>(R_b, n_oe, bo, x, g2, lb2,
                                                h2b, n_h2);

  // Phase D: FFN chunked (CH rows).
  float* m1 = R_k;
  ushort* hidb = (ushort*)R_v;
  float* m2p = R_v + NE / 4;
  const unsigned long long pstr = (unsigned long long)CH * E_DIM;
  for (int c = 0; c < N_ROWS / CH; ++c) {
    size_t ro = (size_t)c * CH;
    k_gemm_bf16<<<dim3(F_DIM / 128, CH / 128, 1), 256, 0, stream>>>(
        h2b + ro * E_DIM, w1b, m1, E_DIM, F_DIM, E_DIM, 0);
    k_epi_ffn1<<<CH / 4, 256, 0, stream>>>(m1, n_h2 + ro, b1, hidb, n_h3 + ro);
    k_gemm_bf16<<<dim3(E_DIM / 128, CH / 128, 2), 256, 0, stream>>>(
        hidb, w2b, m2p, F_DIM, E_DIM, F_DIM / 2, pstr);
    k_epi_final<<<CH / 4, 256, 0, stream>>>(m2p, m2p + pstr, n_h3 + ro, b2,
                                            R_b + ro * E_DIM, out + ro * E_DIM);
  }
}

// Round 2
// 983.035 us; speedup vs baseline: 1.0968x; 1.0393x over previous
//
// Hyperbolic (Poincare ball) transformer block — MI355X round 7.
// Round-6 + latency-oriented epilogue rework:
//  * Every row-wise epilogue was latency-bound (VALUBusy 46%, HBM 49%,
//    3 serial butterfly chains per row). Now each wave processes 2 ROWS
//    (2x ILP in every shfl step and transcendental chain), bias-only
//    sums are shared, and chains are collapsed analytically:
//      - attnout: sum(z*r) = ps*(cc1*sum(m*r)+cc2*sum(bv*r)) -> 1st+2nd
//        reductions fused into one waveRed<16>; 2 chains total (was 3).
//      - stage1: sum(e^2) expanded via (g^2 v^2, g^2 v, g v b, g^2, g b,
//        b^2) -> single reduction chain (was 2).
//  * FFN2 GEMM: split-K 4 (512 blocks = 2/CU, was 256 = 1/CU which
//    defeated the m97 structure's multi-block overlap). Partials go in
//    R_k (m1 dead after epi_ffn1; exact 32MB fit); epi_final sums 4.
// GEMM inner structure and MFMA attention unchanged.
#include <hip/hip_runtime.h>
#include <math.h>

#define S_DIM 128
#define B_DIM 256
#define E_DIM 512
#define F_DIM 2048
#define N_ROWS (S_DIM * B_DIM) /* 32768 */
#define CH 4096                /* FFN row chunk */
#define PSTR ((size_t)CH * E_DIM)
#define MAXN 0.99999f          /* 1 - 1e-5 */

typedef __bf16 bf16x8 __attribute__((ext_vector_type(8)));
typedef float f32x4 __attribute__((ext_vector_type(4)));

// ---- fast-math helpers (1-instr HW transcendentals) -----------------------
__device__ __forceinline__ float frcp(float x) { return __builtin_amdgcn_rcpf(x); }
__device__ __forceinline__ float frsq(float x) { return __builtin_amdgcn_rsqf(x); }
__device__ __forceinline__ float fexp2(float x) { return __builtin_amdgcn_exp2f(x); }
__device__ __forceinline__ float flog2(float x) { return __builtin_amdgcn_logf(x); }
__device__ __forceinline__ float fatanh(float x) {
  return 0.34657359f * flog2((1.f + x) * frcp(1.f - x));
}
__device__ __forceinline__ float ftanh(float x) {
  float t = fexp2(x * -2.88539008f);
  return (1.f - t) * frcp(1.f + t);
}

__device__ __forceinline__ ushort f2bf(float f) {
  __bf16 h = (__bf16)f;
  return __builtin_bit_cast(ushort, h);
}
__device__ __forceinline__ uint pack2(float a, float b) {
  return (uint)f2bf(a) | ((uint)f2bf(b) << 16);
}

__device__ __forceinline__ void gld16(const ushort* g, ushort* l) {
  __builtin_amdgcn_global_load_lds(
      (const __attribute__((address_space(1))) void*)g,
      (__attribute__((address_space(3))) void*)l, 16, 0, 0);
}

// ---- wave-wide butterfly reduction of K values (all lanes get results) ----
template <int K>
__device__ __forceinline__ void waveRed(float (&v)[K]) {
#pragma unroll
  for (int o = 1; o < 64; o <<= 1) {
#pragma unroll
    for (int i = 0; i < K; ++i) v[i] += __shfl_xor(v[i], o);
  }
}

// ---------------- fp32 -> bf16 convert (weights) ---------------------------
__global__ __launch_bounds__(256) void k_f2bf(const float* __restrict__ in,
                                              ushort* __restrict__ out, int n) {
  for (int i = blockIdx.x * 256 + threadIdx.x; i < n; i += gridDim.x * 256)
    out[i] = f2bf(in[i]);
}

// ---- stage 1: h1 = expmap0(LN(logmap0(x))) -> bf16. 2 rows/wave, 1 chain. -
__global__ __launch_bounds__(256) void k_stage1(const float* __restrict__ x,
                                                const float* __restrict__ g,
                                                const float* __restrict__ bb,
                                                ushort* __restrict__ h,
                                                float* __restrict__ hn) {
  int wv = threadIdx.x >> 6, lane = threadIdx.x & 63;
  int row = blockIdx.x * 8 + wv * 2;
  size_t base = (size_t)row * E_DIM + lane * 8;
  float v[2][8], gv[8], bv[8];
  *(float4*)&v[0][0] = *(const float4*)(x + base);
  *(float4*)&v[0][4] = *(const float4*)(x + base + 4);
  *(float4*)&v[1][0] = *(const float4*)(x + base + E_DIM);
  *(float4*)&v[1][4] = *(const float4*)(x + base + E_DIM + 4);
  *(float4*)&gv[0] = *(const float4*)(g + lane * 8);
  *(float4*)&gv[4] = *(const float4*)(g + lane * 8 + 4);
  *(float4*)&bv[0] = *(const float4*)(bb + lane * 8);
  *(float4*)&bv[4] = *(const float4*)(bb + lane * 8 + 4);
  // per-row: v^2, v, g^2 v^2, g^2 v, g v b  | shared: g^2, g b, b^2
  float s[13];
#pragma unroll
  for (int i = 0; i < 13; ++i) s[i] = 0.f;
#pragma unroll
  for (int i = 0; i < 8; ++i) {
    float gg = gv[i] * gv[i], gb = gv[i] * bv[i];
#pragma unroll
    for (int r2 = 0; r2 < 2; ++r2) {
      float vv = v[r2][i];
      s[r2 * 5 + 0] += vv * vv;
      s[r2 * 5 + 1] += vv;
      s[r2 * 5 + 2] += vv * vv * gg;
      s[r2 * 5 + 3] += vv * gg;
      s[r2 * 5 + 4] += vv * gb;
    }
    s[10] += gg; s[11] += gb; s[12] += bv[i] * bv[i];
  }
  waveRed<13>(s);
#pragma unroll
  for (int r2 = 0; r2 < 2; ++r2) {
    float T0 = s[r2 * 5 + 0], T1 = s[r2 * 5 + 1], T2 = s[r2 * 5 + 2];
    float T3 = s[r2 * 5 + 3], T4 = s[r2 * 5 + 4];
    float se = T0 + 1e-30f;
    float rn = frsq(se);
    float n = se * rn;
    float a = fatanh(fminf(n, MAXN)) * rn;
    float mu = a * T1 * (1.f / 512.f);
    float var = fmaxf(a * a * T0 * (1.f / 512.f) - mu * mu, 0.f);
    float rstd = frsq(var + 1e-5f);
    float A = a * rstd, B = -mu * rstd;
    // sum(e^2), e = A*v*g + B*g + b  (analytic, no second data pass)
    float se2 = fmaxf(A * A * T2 + 2.f * A * B * T3 + 2.f * A * T4 +
                          B * B * s[10] + 2.f * B * s[11] + s[12], 0.f) + 1e-30f;
    float rn2 = frsq(se2);
    float n2 = se2 * rn2;
    float th = ftanh(n2);
    float f = th * rn2;
    float e[8];
#pragma unroll
    for (int i = 0; i < 8; ++i) e[i] = (A * v[r2][i] + B) * gv[i] + bv[i];
    uint4 o = {pack2(e[0] * f, e[1] * f), pack2(e[2] * f, e[3] * f),
               pack2(e[4] * f, e[5] * f), pack2(e[6] * f, e[7] * f)};
    *reinterpret_cast<uint4*>(h + base + r2 * E_DIM) = o;
    if (lane == 0) hn[row + r2] = th;
  }
}

// -------- bf16 MFMA GEMM: C[n][m] = sum_k A[n][k]*B[m][k], C fp32 ----------
__global__ __launch_bounds__(256) void k_gemm_bf16(
    const ushort* __restrict__ A, const ushort* __restrict__ B,
    float* __restrict__ C, int K, int M, int kseg,
    unsigned long long partStride) {
  __shared__ __align__(16) ushort As[128 * 32];
  __shared__ __align__(16) ushort Bs[128 * 32];
  int tid = threadIdx.x;
  int w = tid >> 6, lane = tid & 63;
  int wm = w >> 1, wn = w & 1;
  size_t row0 = (size_t)blockIdx.y * 128;
  size_t col0 = (size_t)blockIdx.x * 128;
  int k0 = blockIdx.z * kseg;

  const ushort* gA =
      A + (row0 + w * 32 + (lane >> 2)) * (size_t)K + (lane & 3) * 8 + k0;
  const ushort* gB =
      B + (col0 + w * 32 + (lane >> 2)) * (size_t)K + (lane & 3) * 8 + k0;
  ushort* lA = As + (w * 32) * 32;
  ushort* lB = Bs + (w * 32) * 32;
  const int rowK16 = 16 * K;

  int fro = (lane & 15) * 32 + (lane >> 4) * 8;
  const ushort* raA = As + (wm * 64) * 32 + fro;
  const ushort* raB = Bs + (wn * 64) * 32 + fro;

  f32x4 zero = {0.f, 0.f, 0.f, 0.f};
  f32x4 acc[4][4];
#pragma unroll
  for (int i = 0; i < 4; ++i)
#pragma unroll
    for (int j = 0; j < 4; ++j) acc[i][j] = zero;

  for (int kt = 0; kt < kseg; kt += 32) {
    __syncthreads();
    gld16(gA + kt, lA);
    gld16(gA + kt + rowK16, lA + 16 * 32);
    gld16(gB + kt, lB);
    gld16(gB + kt + rowK16, lB + 16 * 32);
    __syncthreads();
    bf16x8 af[4], bfv[4];
#pragma unroll
    for (int t = 0; t < 4; ++t) {
      af[t] = *reinterpret_cast<const bf16x8*>(raA + t * 512);
      bfv[t] = *reinterpret_cast<const bf16x8*>(raB + t * 512);
    }
#pragma unroll
    for (int i = 0; i < 4; ++i)
#pragma unroll
      for (int j = 0; j < 4; ++j)
        acc[i][j] = __builtin_amdgcn_mfma_f32_16x16x32_bf16(af[i], bfv[j],
                                                            acc[i][j], 0, 0, 0);
  }
  float* Cz = C + (size_t)blockIdx.z * partStride;
  int crow = wm * 64 + (lane >> 4) * 4;
  int ccol = (int)col0 + wn * 64 + (lane & 15);
#pragma unroll
  for (int ti = 0; ti < 4; ++ti) {
    size_t r = row0 + crow + ti * 16;
#pragma unroll
    for (int tj = 0; tj < 4; ++tj) {
      int cc = ccol + tj * 16;
#pragma unroll
      for (int reg = 0; reg < 4; ++reg)
        Cz[(r + reg) * (size_t)M + cc] = acc[ti][tj][reg];
    }
  }
}

// ---- QKV epilogue: logmap0(projx(mobius_add(mv,b))). 2 rows/wave. ---------
__global__ __launch_bounds__(256) void k_epi_qkv(const float* __restrict__ mx,
                                                 const float* __restrict__ xn_arr,
                                                 const float* __restrict__ bias,
                                                 ushort* __restrict__ qout) {
  int wv = threadIdx.x >> 6, lane = threadIdx.x & 63;
  int row = blockIdx.x * 8 + wv * 2;
  size_t base = (size_t)row * E_DIM + lane * 8;
  float m[2][8], bv[8];
  *(float4*)&m[0][0] = *(const float4*)(mx + base);
  *(float4*)&m[0][4] = *(const float4*)(mx + base + 4);
  *(float4*)&m[1][0] = *(const float4*)(mx + base + E_DIM);
  *(float4*)&m[1][4] = *(const float4*)(mx + base + E_DIM + 4);
  *(float4*)&bv[0] = *(const float4*)(bias + lane * 8);
  *(float4*)&bv[4] = *(const float4*)(bias + lane * 8 + 4);
  // per-row: m^2, m*bv | shared: bv^2
  float s[5];
#pragma unroll
  for (int i = 0; i < 5; ++i) s[i] = 0.f;
#pragma unroll
  for (int i = 0; i < 8; ++i) {
#pragma unroll
    for (int r2 = 0; r2 < 2; ++r2) {
      s[r2 * 2 + 0] += m[r2][i] * m[r2][i];
      s[r2 * 2 + 1] += m[r2][i] * bv[i];
    }
    s[4] += bv[i] * bv[i];
  }
  waveRed<5>(s);
#pragma unroll
  for (int r2 = 0; r2 < 2; ++r2) {
    float S0 = s[r2 * 2 + 0], S1 = s[r2 * 2 + 1], S2 = s[4];
    float se = S0 + 1e-30f;
    float rmx = frsq(se);
    float mxn = se * rmx;
    float xn = xn_arr[row + r2];
    float aa = fatanh(fminf(xn, MAXN));
    float tt = ftanh(mxn * frcp(xn) * aa);
    float c = tt * rmx;
    float xy = c * S1, y2 = S2, x2 = tt * tt;
    float c1 = 1.f + 2.f * xy + y2, c2 = 1.f - x2;
    float iden = frcp(fmaxf(1.f + 2.f * xy + x2 * y2, 1e-15f));
    float cc1 = c1 * c * iden, cc2 = c2 * iden;
    float un2 = fmaxf(cc1 * cc1 * S0 + 2.f * cc1 * cc2 * S1 + cc2 * cc2 * S2, 0.f);
    float ue = un2 + 1e-30f;
    float run = frsq(ue);
    float un = ue * run;
    float ne = fminf(un, MAXN);
    float f = fatanh(ne) * run;
    float u[8];
#pragma unroll
    for (int i = 0; i < 8; ++i) u[i] = (cc1 * m[r2][i] + cc2 * bv[i]) * f;
    uint4 o = {pack2(u[0], u[1]), pack2(u[2], u[3]), pack2(u[4], u[5]),
               pack2(u[6], u[7])};
    *reinterpret_cast<uint4*>(qout + base + r2 * E_DIM) = o;
  }
}

// ---- attention: per (b,h) MFMA tile (unchanged) ---------------------------
__global__ __launch_bounds__(256) void k_attn(const ushort* __restrict__ q,
                                              const ushort* __restrict__ k,
                                              const ushort* __restrict__ v,
                                              float* __restrict__ o) {
  __shared__ __align__(16) ushort smem[27136];
  ushort* Qs = smem;
  ushort* Ks = smem + 9216;
  ushort* VTs = smem + 18432;
  ushort* Ps = smem;
  int bh = blockIdx.x;
  int b = bh >> 3, h = bh & 7;
  int tid = threadIdx.x;
  int w = tid >> 6, lane = tid & 63;
  const size_t BE = (size_t)B_DIM * E_DIM;
  size_t gbase = (size_t)b * E_DIM + (size_t)h * 64;

  {
    int s = tid >> 1, half = (tid & 1) * 32;
    const ushort* qr = q + gbase + (size_t)s * BE + half;
    const ushort* kr = k + gbase + (size_t)s * BE + half;
    const ushort* vr = v + gbase + (size_t)s * BE + half;
#pragma unroll
    for (int j = 0; j < 4; ++j) {
      *reinterpret_cast<uint4*>(&Qs[s * 72 + half + j * 8]) =
          *reinterpret_cast<const uint4*>(qr + j * 8);
      *reinterpret_cast<uint4*>(&Ks[s * 72 + half + j * 8]) =
          *reinterpret_cast<const uint4*>(kr + j * 8);
    }
    ushort tv[32];
#pragma unroll
    for (int j = 0; j < 4; ++j)
      *reinterpret_cast<uint4*>(&tv[j * 8]) =
          *reinterpret_cast<const uint4*>(vr + j * 8);
#pragma unroll
    for (int d = 0; d < 32; ++d) VTs[(half + d) * 136 + s] = tv[d];
  }
  __syncthreads();

  f32x4 zero = {0.f, 0.f, 0.f, 0.f};
  f32x4 sacc[2][8];
#pragma unroll
  for (int i = 0; i < 2; ++i)
#pragma unroll
    for (int j = 0; j < 8; ++j) sacc[i][j] = zero;
  {
    const ushort* qb = Qs + (w * 32 + (lane & 15)) * 72 + (lane >> 4) * 8;
    const ushort* kb = Ks + (lane & 15) * 72 + (lane >> 4) * 8;
#pragma unroll
    for (int kk = 0; kk < 2; ++kk) {
      bf16x8 a0 = *reinterpret_cast<const bf16x8*>(qb + kk * 32);
      bf16x8 a1 = *reinterpret_cast<const bf16x8*>(qb + 16 * 72 + kk * 32);
#pragma unroll
      for (int tj = 0; tj < 8; ++tj) {
        bf16x8 bf = *reinterpret_cast<const bf16x8*>(kb + tj * 16 * 72 + kk * 32);
        sacc[0][tj] = __builtin_amdgcn_mfma_f32_16x16x32_bf16(a0, bf,
                                                              sacc[0][tj], 0, 0, 0);
        sacc[1][tj] = __builtin_amdgcn_mfma_f32_16x16x32_bf16(a1, bf,
                                                              sacc[1][tj], 0, 0, 0);
      }
    }
  }

#pragma unroll
  for (int ti = 0; ti < 2; ++ti) {
#pragma unroll
    for (int r = 0; r < 4; ++r) {
      float mx = -1e30f;
#pragma unroll
      for (int tj = 0; tj < 8; ++tj) mx = fmaxf(mx, sacc[ti][tj][r]);
      mx = fmaxf(mx, __shfl_xor(mx, 1));
      mx = fmaxf(mx, __shfl_xor(mx, 2));
      mx = fmaxf(mx, __shfl_xor(mx, 4));
      mx = fmaxf(mx, __shfl_xor(mx, 8));
      float l = 0.f;
#pragma unroll
      for (int tj = 0; tj < 8; ++tj) {
        float e = fexp2((sacc[ti][tj][r] - mx) * (0.125f * 1.44269504f));
        sacc[ti][tj][r] = e;
        l += e;
      }
      l += __shfl_xor(l, 1);
      l += __shfl_xor(l, 2);
      l += __shfl_xor(l, 4);
      l += __shfl_xor(l, 8);
      float inv = frcp(l);
#pragma unroll
      for (int tj = 0; tj < 8; ++tj) sacc[ti][tj][r] *= inv;
    }
  }

  __syncthreads();
  {
    int qr0 = w * 32 + (lane >> 4) * 4;
    int kc = lane & 15;
#pragma unroll
    for (int ti = 0; ti < 2; ++ti)
#pragma unroll
      for (int tj = 0; tj < 8; ++tj)
#pragma unroll
        for (int r = 0; r < 4; ++r)
          Ps[(qr0 + ti * 16 + r) * 136 + tj * 16 + kc] =
              f2bf(sacc[ti][tj][r]);
  }
  __syncthreads();

  f32x4 oacc[2][4];
#pragma unroll
  for (int i = 0; i < 2; ++i)
#pragma unroll
    for (int j = 0; j < 4; ++j) oacc[i][j] = zero;
  {
    const ushort* pb = Ps + (w * 32 + (lane & 15)) * 136 + (lane >> 4) * 8;
    const ushort* vb = VTs + (lane & 15) * 136 + (lane >> 4) * 8;
#pragma unroll
    for (int kk = 0; kk < 4; ++kk) {
      bf16x8 a0 = *reinterpret_cast<const bf16x8*>(pb + kk * 32);
      bf16x8 a1 = *reinterpret_cast<const bf16x8*>(pb + 16 * 136 + kk * 32);
#pragma unroll
      for (int tj = 0; tj < 4; ++tj) {
        bf16x8 bv = *reinterpret_cast<const bf16x8*>(vb + tj * 16 * 136 + kk * 32);
        oacc[0][tj] = __builtin_amdgcn_mfma_f32_16x16x32_bf16(a0, bv,
                                                              oacc[0][tj], 0, 0, 0);
        oacc[1][tj] = __builtin_amdgcn_mfma_f32_16x16x32_bf16(a1, bv,
                                                              oacc[1][tj], 0, 0, 0);
      }
    }
  }

  {
    int qr0 = w * 32 + (lane >> 4) * 4;
    int dc = lane & 15;
#pragma unroll
    for (int ti = 0; ti < 2; ++ti)
#pragma unroll
      for (int tj = 0; tj < 4; ++tj)
#pragma unroll
        for (int r = 0; r < 4; ++r)
          o[(size_t)(qr0 + ti * 16 + r) * BE + gbase + tj * 16 + dc] =
              oacc[ti][tj][r];
  }
}

// ---- expmap0 rowwise, 2 rows/wave ----------------------------------------
__global__ __launch_bounds__(256) void k_expmap_rows(const float* __restrict__ in,
                                                     ushort* __restrict__ out,
                                                     float* __restrict__ nrm) {
  int wv = threadIdx.x >> 6, lane = threadIdx.x & 63;
  int row = blockIdx.x * 8 + wv * 2;
  size_t base = (size_t)row * E_DIM + lane * 8;
  float v[2][8];
  *(float4*)&v[0][0] = *(const float4*)(in + base);
  *(float4*)&v[0][4] = *(const float4*)(in + base + 4);
  *(float4*)&v[1][0] = *(const float4*)(in + base + E_DIM);
  *(float4*)&v[1][4] = *(const float4*)(in + base + E_DIM + 4);
  float s[2] = {0.f, 0.f};
#pragma unroll
  for (int i = 0; i < 8; ++i) {
    s[0] += v[0][i] * v[0][i];
    s[1] += v[1][i] * v[1][i];
  }
  waveRed<2>(s);
#pragma unroll
  for (int r2 = 0; r2 < 2; ++r2) {
    float se = s[r2] + 1e-30f;
    float rn = frsq(se);
    float n = se * rn;
    float th = ftanh(n);
    float f = th * rn;
    uint4 o = {pack2(v[r2][0] * f, v[r2][1] * f), pack2(v[r2][2] * f, v[r2][3] * f),
               pack2(v[r2][4] * f, v[r2][5] * f), pack2(v[r2][6] * f, v[r2][7] * f)};
    *reinterpret_cast<uint4*>(out + base + r2 * E_DIM) = o;
    if (lane == 0) nrm[row + r2] = th;
  }
}

// ---- attn-out epilogue, 2 rows/wave, 2 chains (was 3) ---------------------
__global__ __launch_bounds__(256) void k_epi_attnout(
    float* __restrict__ mo, const float* __restrict__ xn_arr,
    const float* __restrict__ bo, const float* __restrict__ xin,
    const float* __restrict__ g2, const float* __restrict__ b2,
    ushort* __restrict__ h2, float* __restrict__ h2n) {
  int wv = threadIdx.x >> 6, lane = threadIdx.x & 63;
  int row = blockIdx.x * 8 + wv * 2;
  size_t base = (size_t)row * E_DIM + lane * 8;
  float m[2][8], bv[8], r[2][8], gv[8], b2v[8];
  *(float4*)&m[0][0] = *(const float4*)(mo + base);
  *(float4*)&m[0][4] = *(const float4*)(mo + base + 4);
  *(float4*)&m[1][0] = *(const float4*)(mo + base + E_DIM);
  *(float4*)&m[1][4] = *(const float4*)(mo + base + E_DIM + 4);
  *(float4*)&r[0][0] = *(const float4*)(xin + base);
  *(float4*)&r[0][4] = *(const float4*)(xin + base + 4);
  *(float4*)&r[1][0] = *(const float4*)(xin + base + E_DIM);
  *(float4*)&r[1][4] = *(const float4*)(xin + base + E_DIM + 4);
  *(float4*)&bv[0] = *(const float4*)(bo + lane * 8);
  *(float4*)&bv[4] = *(const float4*)(bo + lane * 8 + 4);
  *(float4*)&gv[0] = *(const float4*)(g2 + lane * 8);
  *(float4*)&gv[4] = *(const float4*)(g2 + lane * 8 + 4);
  *(float4*)&b2v[0] = *(const float4*)(b2 + lane * 8);
  *(float4*)&b2v[4] = *(const float4*)(b2 + lane * 8 + 4);
  // per-row: m^2, m*bv, m, m*r, bv*r, r^2, r | shared: bv^2, bv
  float s[16];
#pragma unroll
  for (int i = 0; i < 16; ++i) s[i] = 0.f;
#pragma unroll
  for (int i = 0; i < 8; ++i) {
#pragma unroll
    for (int r2 = 0; r2 < 2; ++r2) {
      float mm = m[r2][i], rr = r[r2][i];
      s[r2 * 7 + 0] += mm * mm;
      s[r2 * 7 + 1] += mm * bv[i];
      s[r2 * 7 + 2] += mm;
      s[r2 * 7 + 3] += mm * rr;
      s[r2 * 7 + 4] += bv[i] * rr;
      s[r2 * 7 + 5] += rr * rr;
      s[r2 * 7 + 6] += rr;
    }
    s[14] += bv[i] * bv[i];
    s[15] += bv[i];
  }
  waveRed<16>(s);
  float e[2][8];
  float s3[2] = {0.f, 0.f};
#pragma unroll
  for (int r2 = 0; r2 < 2; ++r2) {
    float S0 = s[r2 * 7 + 0], Smb = s[r2 * 7 + 1], Sm = s[r2 * 7 + 2];
    float Smr = s[r2 * 7 + 3], Sbr = s[r2 * 7 + 4], Sr2 = s[r2 * 7 + 5];
    float Sr = s[r2 * 7 + 6], Sb2 = s[14], Sb = s[15];
    float se = S0 + 1e-30f;
    float rmx = frsq(se);
    float mxn = se * rmx;
    float xn = xn_arr[row + r2];
    float aa = fatanh(fminf(xn, MAXN));
    float tt = ftanh(mxn * frcp(xn) * aa);
    float c = tt * rmx;
    float xy = c * Smb, y2 = Sb2, x2 = tt * tt;
    float c1 = 1.f + 2.f * xy + y2, c2 = 1.f - x2;
    float iden = frcp(fmaxf(1.f + 2.f * xy + x2 * y2, 1e-15f));
    float cc1 = c1 * c * iden, cc2 = c2 * iden;
    float un2 = fmaxf(cc1 * cc1 * S0 + 2.f * cc1 * cc2 * Smb + cc2 * cc2 * Sb2, 0.f);
    float ue = un2 + 1e-30f;
    float run = frsq(ue);
    float un = ue * run;
    float ps = un > MAXN ? MAXN * run : 1.f;
    float zn = fminf(un, MAXN);
    float sumz = ps * (cc1 * Sm + cc2 * Sb);
    // mobius_add(z, r) with z = ps*(cc1*m + cc2*bv):
    float xy2 = ps * (cc1 * Smr + cc2 * Sbr);  // sum(z*r) analytic
    float y22 = Sr2, x22 = zn * zn;
    float d1 = 1.f + 2.f * xy2 + y22, d2 = 1.f - x22;
    float iden2 = frcp(fmaxf(1.f + 2.f * xy2 + x22 * y22, 1e-15f));
    float wn2 = fmaxf(iden2 * iden2 *
                          (d1 * d1 * x22 + 2.f * d1 * d2 * xy2 + d2 * d2 * y22),
                      0.f);
    float we = wn2 + 1e-30f;
    float rwn = frsq(we);
    float wn = we * rwn;
    float ps2 = wn > MAXN ? MAXN * rwn : 1.f;
    float P = d1 * iden2 * ps2 * ps * cc1;
    float Q = d1 * iden2 * ps2 * ps * cc2;
    float R = d2 * iden2 * ps2;
    float w[8];
#pragma unroll
    for (int i = 0; i < 8; ++i) w[i] = P * m[r2][i] + Q * bv[i] + R * r[r2][i];
    *(float4*)(mo + base + r2 * E_DIM) = *(float4*)&w[0];
    *(float4*)(mo + base + r2 * E_DIM + 4) = *(float4*)&w[4];
    // logmap0 -> LN2 -> (expmap scale after 2nd reduction)
    float ne = fminf(wn, MAXN);
    float ath = fatanh(ne);
    float lf = ath * frcp(ne);
    float sumw = ps2 * iden2 * (d1 * sumz + d2 * Sr);
    float mu = lf * sumw * (1.f / 512.f);
    float var = fmaxf(ath * ath * (1.f / 512.f) - mu * mu, 0.f);
    float rstd = frsq(var + 1e-5f);
#pragma unroll
    for (int i = 0; i < 8; ++i) {
      e[r2][i] = (lf * w[i] - mu) * rstd * gv[i] + b2v[i];
      s3[r2] += e[r2][i] * e[r2][i];
    }
  }
  waveRed<2>(s3);
#pragma unroll
  for (int r2 = 0; r2 < 2; ++r2) {
    float s3e = s3[r2] + 1e-30f;
    float rn3 = frsq(s3e);
    float n3 = s3e * rn3;
    float en = ftanh(n3);
    float f = en * rn3;
    if (en > MAXN) f *= MAXN * frcp(en);
    uint4 o = {pack2(e[r2][0] * f, e[r2][1] * f), pack2(e[r2][2] * f, e[r2][3] * f),
               pack2(e[r2][4] * f, e[r2][5] * f), pack2(e[r2][6] * f, e[r2][7] * f)};
    *reinterpret_cast<uint4*>(h2 + base + r2 * E_DIM) = o;
    if (lane == 0) h2n[row + r2] = fminf(en, MAXN);
  }
}

// ---- FFN1 epilogue (2 rows/wave of F=2048) -> bf16 ------------------------
__global__ __launch_bounds__(256) void k_epi_ffn1(const float* __restrict__ mr_,
                                                  const float* __restrict__ xn_arr,
                                                  const float* __restrict__ bias,
                                                  ushort* __restrict__ hid,
                                                  float* __restrict__ hn_out) {
  int wv = threadIdx.x >> 6, lane = threadIdx.x & 63;
  int row = blockIdx.x * 8 + wv * 2;
  const float* mr = mr_ + (size_t)row * F_DIM + lane * 32;
  const float* br = bias + lane * 32;
  float m[2][32], bv[32];
#pragma unroll
  for (int j = 0; j < 8; ++j) {
    *(float4*)&m[0][j * 4] = *(const float4*)(mr + j * 4);
    *(float4*)&m[1][j * 4] = *(const float4*)(mr + F_DIM + j * 4);
    *(float4*)&bv[j * 4] = *(const float4*)(br + j * 4);
  }
  // per-row: m^2, m*bv | shared: bv^2
  float s[5];
#pragma unroll
  for (int i = 0; i < 5; ++i) s[i] = 0.f;
#pragma unroll
  for (int i = 0; i < 32; ++i) {
#pragma unroll
    for (int r2 = 0; r2 < 2; ++r2) {
      s[r2 * 2 + 0] += m[r2][i] * m[r2][i];
      s[r2 * 2 + 1] += m[r2][i] * bv[i];
    }
    s[4] += bv[i] * bv[i];
  }
  waveRed<5>(s);
  float s2[2] = {0.f, 0.f};
#pragma unroll
  for (int r2 = 0; r2 < 2; ++r2) {
    float S0 = s[r2 * 2 + 0], S1 = s[r2 * 2 + 1], S2 = s[4];
    float se = S0 + 1e-30f;
    float rmx = frsq(se);
    float mxn = se * rmx;
    float xn = xn_arr[row + r2];
    float aa = fatanh(fminf(xn, MAXN));
    float tt = ftanh(mxn * frcp(xn) * aa);
    float c = tt * rmx;
    float xy = c * S1, y2 = S2, x2 = tt * tt;
    float c1 = 1.f + 2.f * xy + y2, c2 = 1.f - x2;
    float iden = frcp(fmaxf(1.f + 2.f * xy + x2 * y2, 1e-15f));
    float cc1 = c1 * c * iden, cc2 = c2 * iden;
    float un2 = fmaxf(cc1 * cc1 * S0 + 2.f * cc1 * cc2 * S1 + cc2 * cc2 * S2, 0.f);
    float ue = un2 + 1e-30f;
    float run = frsq(ue);
    float un = ue * run;
    float zn = fminf(un, MAXN);
    float lf = fatanh(zn) * run;
#pragma unroll
    for (int i = 0; i < 32; ++i) {
      m[r2][i] = fmaxf((cc1 * m[r2][i] + cc2 * bv[i]) * lf, 0.f);
      s2[r2] += m[r2][i] * m[r2][i];
    }
  }
  waveRed<2>(s2);
#pragma unroll
  for (int r2 = 0; r2 < 2; ++r2) {
    float s2e = s2[r2] + 1e-30f;
    float rrn = frsq(s2e);
    float rn = s2e * rrn;
    float en = ftanh(rn);
    float f = en * rrn;
    if (en > MAXN) f *= MAXN * frcp(en);
    ushort* hr = hid + (size_t)(row + r2) * F_DIM + lane * 32;
#pragma unroll
    for (int j = 0; j < 4; ++j) {
      uint4 o = {pack2(m[r2][j * 8 + 0] * f, m[r2][j * 8 + 1] * f),
                 pack2(m[r2][j * 8 + 2] * f, m[r2][j * 8 + 3] * f),
                 pack2(m[r2][j * 8 + 4] * f, m[r2][j * 8 + 5] * f),
                 pack2(m[r2][j * 8 + 6] * f, m[r2][j * 8 + 7] * f)};
      *reinterpret_cast<uint4*>(hr + j * 8) = o;
    }
    if (lane == 0) hn_out[row + r2] = fminf(en, MAXN);
  }
}

// ---- final epilogue (2 rows/wave): 4-way split-K sum + man_linear(W2) +
// mob_relu + residual mobius_add + projx -> out fp32 ------------------------
__global__ __launch_bounds__(256) void k_epi_final(
    const float* __restrict__ m2, const float* __restrict__ xn_arr,
    const float* __restrict__ bias, const float* __restrict__ res,
    float* __restrict__ out) {
  int wv = threadIdx.x >> 6, lane = threadIdx.x & 63;
  int row = blockIdx.x * 8 + wv * 2;
  size_t base = (size_t)row * E_DIM + lane * 8;
  float m[2][8], bv[8], q[2][8];
#pragma unroll
  for (int r2 = 0; r2 < 2; ++r2) {
    float ta[8], tb[8];
    *(float4*)&ta[0] = *(const float4*)(m2 + base + r2 * E_DIM);
    *(float4*)&ta[4] = *(const float4*)(m2 + base + r2 * E_DIM + 4);
    *(float4*)&tb[0] = *(const float4*)(m2 + PSTR + base + r2 * E_DIM);
    *(float4*)&tb[4] = *(const float4*)(m2 + PSTR + base + r2 * E_DIM + 4);
    float tc[8], td[8];
    *(float4*)&tc[0] = *(const float4*)(m2 + 2 * PSTR + base + r2 * E_DIM);
    *(float4*)&tc[4] = *(const float4*)(m2 + 2 * PSTR + base + r2 * E_DIM + 4);
    *(float4*)&td[0] = *(const float4*)(m2 + 3 * PSTR + base + r2 * E_DIM);
    *(float4*)&td[4] = *(const float4*)(m2 + 3 * PSTR + base + r2 * E_DIM + 4);
#pragma unroll
    for (int i = 0; i < 8; ++i) m[r2][i] = (ta[i] + tb[i]) + (tc[i] + td[i]);
    *(float4*)&q[r2][0] = *(const float4*)(res + base + r2 * E_DIM);
    *(float4*)&q[r2][4] = *(const float4*)(res + base + r2 * E_DIM + 4);
  }
  *(float4*)&bv[0] = *(const float4*)(bias + lane * 8);
  *(float4*)&bv[4] = *(const float4*)(bias + lane * 8 + 4);
  // per-row: m^2, m*bv, q^2 | shared: bv^2
  float s[7];
#pragma unroll
  for (int i = 0; i < 7; ++i) s[i] = 0.f;
#pragma unroll
  for (int i = 0; i < 8; ++i) {
#pragma unroll
    for (int r2 = 0; r2 < 2; ++r2) {
      s[r2 * 3 + 0] += m[r2][i] * m[r2][i];
      s[r2 * 3 + 1] += m[r2][i] * bv[i];
      s[r2 * 3 + 2] += q[r2][i] * q[r2][i];
    }
    s[6] += bv[i] * bv[i];
  }
  waveRed<7>(s);
  float r[2][8];
  float s2[4];
#pragma unroll
  for (int i = 0; i < 4; ++i) s2[i] = 0.f;
#pragma unroll
  for (int r2 = 0; r2 < 2; ++r2) {
    float S0 = s[r2 * 3 + 0], S1 = s[r2 * 3 + 1], S2 = s[6];
    float se = S0 + 1e-30f;
    float rmx = frsq(se);
    float mxn = se * rmx;
    float xn = xn_arr[row + r2];
    float aa = fatanh(fminf(xn, MAXN));
    float tt = ftanh(mxn * frcp(xn) * aa);
    float c = tt * rmx;
    float xy = c * S1, y2 = S2, x2 = tt * tt;
    float c1 = 1.f + 2.f * xy + y2, c2 = 1.f - x2;
    float iden = frcp(fmaxf(1.f + 2.f * xy + x2 * y2, 1e-15f));
    float cc1 = c1 * c * iden, cc2 = c2 * iden;
    float un2 = fmaxf(cc1 * cc1 * S0 + 2.f * cc1 * cc2 * S1 + cc2 * cc2 * S2, 0.f);
    float ue = un2 + 1e-30f;
    float run = frsq(ue);
    float un = ue * run;
    float zn = fminf(un, MAXN);
    float lf = fatanh(zn) * run;
#pragma unroll
    for (int i = 0; i < 8; ++i) {
      r[r2][i] = fmaxf((cc1 * m[r2][i] + cc2 * bv[i]) * lf, 0.f);
      s2[r2 * 2 + 0] += r[r2][i] * r[r2][i];
      s2[r2 * 2 + 1] += r[r2][i] * q[r2][i];
    }
  }
  waveRed<4>(s2);
#pragma unroll
  for (int r2 = 0; r2 < 2; ++r2) {
    float s2e = s2[r2 * 2 + 0] + 1e-30f;
    float rrn = frsq(s2e);
    float rn = s2e * rrn;
    float en = ftanh(rn);
    float f = en * rrn;
    if (en > MAXN) f *= MAXN * frcp(en);
    float hn = fminf(en, MAXN);
    float xy2 = f * s2[r2 * 2 + 1], y22 = s[r2 * 3 + 2], x22 = hn * hn;
    float d1 = 1.f + 2.f * xy2 + y22, d2 = 1.f - x22;
    float iden2 = frcp(fmaxf(1.f + 2.f * xy2 + x22 * y22, 1e-15f));
    float wn2 = fmaxf(iden2 * iden2 *
                          (d1 * d1 * x22 + 2.f * d1 * d2 * xy2 + d2 * d2 * y22),
                      0.f);
    float we = wn2 + 1e-30f;
    float rwn = frsq(we);
    float wn = we * rwn;
    float ps2 = wn > MAXN ? MAXN * rwn : 1.f;
    float w[8];
#pragma unroll
    for (int i = 0; i < 8; ++i)
      w[i] = (d1 * r[r2][i] * f + d2 * q[r2][i]) * iden2 * ps2;
    *(float4*)(out + base + r2 * E_DIM) = *(float4*)&w[0];
    *(float4*)(out + base + r2 * E_DIM + 4) = *(float4*)&w[4];
  }
}

extern "C" void kernel_launch(void* const* d_in, const int* in_sizes, int n_in,
                              void* d_out, int out_size, void* d_ws,
                              size_t ws_size, hipStream_t stream) {
  const float* x   = (const float*)d_in[0];
  const float* g1  = (const float*)d_in[1];
  const float* lb1 = (const float*)d_in[2];
  const float* g2  = (const float*)d_in[3];
  const float* lb2 = (const float*)d_in[4];
  const float* Wq  = (const float*)d_in[5];
  const float* bq  = (const float*)d_in[6];
  const float* Wk  = (const float*)d_in[7];
  const float* bk  = (const float*)d_in[8];
  const float* Wv  = (const float*)d_in[9];
  const float* bv  = (const float*)d_in[10];
  const float* Wo  = (const float*)d_in[11];
  const float* bo  = (const float*)d_in[12];
  const float* W1  = (const float*)d_in[13];
  const float* b1  = (const float*)d_in[14];
  const float* W2  = (const float*)d_in[15];
  const float* b2  = (const float*)d_in[16];
  float* out = (float*)d_out;
  float* ws = (float*)d_ws;

  const size_t NE = (size_t)N_ROWS * E_DIM;          // 16,777,216
  const size_t WF = (4 * (size_t)E_DIM * E_DIM +
                     2 * (size_t)F_DIM * E_DIM) / 2; // 1,572,864 floats
  float* R_b = ws;                   // NE: mx fp32 / attn-out / mo / res2
  float* R_a = ws + NE;              // NE/2: h1_bf16 -> oe_bf16
  float* R_q = ws + NE + NE / 2;     // NE/2: q_bf16 -> h2_bf16
  float* R_k = ws + 2 * NE;          // NE/2: k_bf16 -> m1 fp32 -> m2 partials
  float* R_v = ws + 2 * NE + NE / 2; // NE/2: v_bf16 -> hid_bf16
  ushort* wqb = (ushort*)(ws + 3 * NE);
  ushort* wkb = wqb + (size_t)E_DIM * E_DIM;
  ushort* wvb = wkb + (size_t)E_DIM * E_DIM;
  ushort* wob = wvb + (size_t)E_DIM * E_DIM;
  ushort* w1b = wob + (size_t)E_DIM * E_DIM;
  ushort* w2b = w1b + (size_t)F_DIM * E_DIM;
  float* n_h1 = ws + 3 * NE + WF;
  float* n_oe = n_h1 + N_ROWS;
  float* n_h2 = n_oe + N_ROWS;
  float* n_h3 = n_h2 + N_ROWS;
  const size_t need = (3 * NE + WF + 4 * (size_t)N_ROWS) * sizeof(float);
  if (ws_size < need) return;

  k_f2bf<<<256, 256, 0, stream>>>(Wq, wqb, E_DIM * E_DIM);
  k_f2bf<<<256, 256, 0, stream>>>(Wk, wkb, E_DIM * E_DIM);
  k_f2bf<<<256, 256, 0, stream>>>(Wv, wvb, E_DIM * E_DIM);
  k_f2bf<<<256, 256, 0, stream>>>(Wo, wob, E_DIM * E_DIM);
  k_f2bf<<<512, 256, 0, stream>>>(W1, w1b, F_DIM * E_DIM);
  k_f2bf<<<512, 256, 0, stream>>>(W2, w2b, F_DIM * E_DIM);

  ushort* h1b = (ushort*)R_a;
  ushort* qb = (ushort*)R_q;
  ushort* kb = (ushort*)R_k;
  ushort* vb = (ushort*)R_v;

  // Phase A: stage1 + QKV projections
  k_stage1<<<N_ROWS / 8, 256, 0, stream>>>(x, g1, lb1, h1b, n_h1);
  dim3 gQ(E_DIM / 128, N_ROWS / 128, 1);
  k_gemm_bf16<<<gQ, 256, 0, stream>>>(h1b, wqb, R_b, E_DIM, E_DIM, E_DIM, 0);
  k_epi_qkv<<<N_ROWS / 8, 256, 0, stream>>>(R_b, n_h1, bq, qb);
  k_gemm_bf16<<<gQ, 256, 0, stream>>>(h1b, wkb, R_b, E_DIM, E_DIM, E_DIM, 0);
  k_epi_qkv<<<N_ROWS / 8, 256, 0, stream>>>(R_b, n_h1, bk, kb);
  k_gemm_bf16<<<gQ, 256, 0, stream>>>(h1b, wvb, R_b, E_DIM, E_DIM, E_DIM, 0);
  k_epi_qkv<<<N_ROWS / 8, 256, 0, stream>>>(R_b, n_h1, bv, vb);

  // Phase B: MFMA attention -> R_b fp32; expmap0 -> oe bf16 (R_a, h1 dead)
  k_attn<<<B_DIM * 8, 256, 0, stream>>>(qb, kb, vb, R_b);
  ushort* oeb = (ushort*)R_a;
  k_expmap_rows<<<N_ROWS / 8, 256, 0, stream>>>(R_b, oeb, n_oe);

  // Phase C: Wo projection -> R_b; epilogue: res2 in-place, h2 bf16 -> R_q
  ushort* h2b = (ushort*)R_q;
  k_gemm_bf16<<<gQ, 256, 0, stream>>>(oeb, wob, R_b, E_DIM, E_DIM, E_DIM, 0);
  k_epi_attnout<<<N_ROWS / 8, 256, 0, stream>>>(R_b, n_oe, bo, x, g2, lb2,
                                                h2b, n_h2);

  // Phase D: FFN chunked (CH rows). m1 and the 4 FFN2 split-K partials
  // time-share R_k (m1 is dead once epi_ffn1 completes; stream-ordered).
  float* m1 = R_k;
  ushort* hidb = (ushort*)R_v;
  float* m2 = R_k;
  for (int c = 0; c < N_ROWS / CH; ++c) {
    size_t ro = (size_t)c * CH;
    k_gemm_bf16<<<dim3(F_DIM / 128, CH / 128, 1), 256, 0, stream>>>(
        h2b + ro * E_DIM, w1b, m1, E_DIM, F_DIM, E_DIM, 0);
    k_epi_ffn1<<<CH / 8, 256, 0, stream>>>(m1, n_h2 + ro, b1, hidb, n_h3 + ro);
    k_gemm_bf16<<<dim3(E_DIM / 128, CH / 128, 4), 256, 0, stream>>>(
        hidb, w2b, m2, F_DIM, E_DIM, F_DIM / 4, (unsigned long long)PSTR);
    k_epi_final<<<CH / 8, 256, 0, stream>>>(m2, n_h3 + ro, b2,
                                            R_b + ro * E_DIM, out + ro * E_DIM);
  }
}